// Round 7
// baseline (180.179 us; speedup 1.0000x reference)
//
#include <hip/hip_runtime.h>

#define L_SEQ 2048
#define NH 8
#define DIM 64
#define SS 40
#define UU 40
#define NHD 512   // NH*DIM floats between consecutive l rows

#if defined(__has_builtin)
#  if __has_builtin(__builtin_amdgcn_global_load_lds)
#    define HAVE_GLDS 1
#  endif
#endif

#ifdef HAVE_GLDS
#define GLDS16(gp, lp) __builtin_amdgcn_global_load_lds( \
    (const __attribute__((address_space(1))) void*)(gp), \
    (__attribute__((address_space(3))) void*)(lp), 16, 0, 0)
#endif

// ======================= device bodies =======================

// m-score: wave handles one (b,l), all 8 heads, 40 samples.
// K rows staged to per-wave LDS region via global_load_lds DMA (no data VGPRs ->
// 20 outstanding 1KB loads per wave; latency hidden, L2-BW bound).
__device__ __forceinline__ void m_body(const float* __restrict__ Qg,
                                       const float* __restrict__ Kg,
                                       const int* __restrict__ idx,
                                       float* __restrict__ M,
                                       int bx, int tid, float* ksm) {
    int w = tid >> 6, lane = tid & 63;
    int b = bx & 3;                       // XCD-pinned: bx%8 in {b, b+4}
    int l = (bx >> 2) * 4 + w;
    int h = lane >> 3, c = lane & 7;
    float* kw = ksm + w * 5120;           // 20KB per-wave region (10 rows)

    const float* Qp = Qg + ((size_t)(b * L_SEQ + l) * NH + h) * DIM + c * 8;
    float4 q0 = *(const float4*)Qp;
    float4 q1 = *(const float4*)(Qp + 4);
    int kidx = idx[l * SS + (lane < SS ? lane : 0)];  // 40 idx in lanes 0..39
    const float* Kb = Kg + (size_t)b * L_SEQ * NHD;

    float mx = -INFINITY, sm = 0.f;
    for (int sb = 0; sb < 4; ++sb) {
        // stage 10 K rows (2KB each, contiguous) into this wave's region
        #pragma unroll
        for (int j = 0; j < 10; ++j) {
            int ki = __shfl(kidx, sb * 10 + j);
            const float* g = Kb + (size_t)ki * NHD;
#ifdef HAVE_GLDS
            GLDS16(g + lane * 4, kw + j * 512);
            GLDS16(g + 256 + lane * 4, kw + j * 512 + 256);
#else
            *(float4*)(kw + j * 512 + lane * 4)       = *(const float4*)(g + lane * 4);
            *(float4*)(kw + j * 512 + 256 + lane * 4) = *(const float4*)(g + 256 + lane * 4);
#endif
        }
        asm volatile("s_waitcnt vmcnt(0) lgkmcnt(0)" ::: "memory");
        #pragma unroll
        for (int j = 0; j < 10; ++j) {
            const float* src = kw + j * 512 + lane * 8;  // lane (h,c) -> word h*64+c*8
            float4 ka = *(const float4*)src;
            float4 kb = *(const float4*)(src + 4);
            float d_ = ka.x * q0.x;
            d_ = fmaf(ka.y, q0.y, d_); d_ = fmaf(ka.z, q0.z, d_); d_ = fmaf(ka.w, q0.w, d_);
            d_ = fmaf(kb.x, q1.x, d_); d_ = fmaf(kb.y, q1.y, d_);
            d_ = fmaf(kb.z, q1.z, d_); d_ = fmaf(kb.w, q1.w, d_);
            d_ += __shfl_xor(d_, 1);
            d_ += __shfl_xor(d_, 2);
            d_ += __shfl_xor(d_, 4);
            mx = fmaxf(mx, d_);
            sm += d_;
        }
        asm volatile("s_waitcnt lgkmcnt(0)" ::: "memory");  // ds reads done before re-stage
    }
    if (c == 0) M[((size_t)(b * NH + h)) * L_SEQ + l] = mx - sm * (1.0f / (float)L_SEQ);
}

// csum8 phase A: cs8[bh][c8][d] = sum of 8 V rows
__device__ __forceinline__ void csum8_body(const float* __restrict__ Vg,
                                           float* __restrict__ cs8,
                                           int wid, int lane) {
    int c8 = wid & 255, bh = wid >> 8;
    int b = bh >> 3, h = bh & 7;
    const float* Vp = Vg + ((size_t)(b * L_SEQ + c8 * 8) * NH + h) * DIM + lane;
    float s = 0.f;
    #pragma unroll
    for (int j = 0; j < 8; ++j) s += Vp[(size_t)j * NHD];
    cs8[((size_t)bh * 256 + c8) * 64 + lane] = s;
}

// csum8 phase C: out rows = exclusive prefix + running sum of 8 V rows
__device__ __forceinline__ void write8_body(const float* __restrict__ Vg,
                                            const float* __restrict__ cs8,
                                            float* __restrict__ out,
                                            int wid, int lane) {
    int c8 = wid & 255, bh = wid >> 8;
    int b = bh >> 3, h = bh & 7;
    float run = cs8[((size_t)bh * 256 + c8) * 64 + lane];
    size_t off = ((size_t)(b * L_SEQ + c8 * 8) * NH + h) * DIM + lane;
    const float* Vp = Vg + off;
    float* Op = out + off;
    #pragma unroll
    for (int j = 0; j < 8; ++j) {
        run += Vp[(size_t)j * NHD];
        Op[(size_t)j * NHD] = run;
    }
}

// attention over key-splits (online softmax within block)
__device__ void attn_body(const float* __restrict__ Qg, const float* __restrict__ Kg,
                          const float* __restrict__ Vg, const int* __restrict__ Mtop,
                          float* __restrict__ pm, float* __restrict__ pl,
                          float* __restrict__ pO, float* __restrict__ out,
                          int nsplit, int direct, int bx, int tid,
                          float* qs, float* ks, float* ps,
                          float* mm, float* ll, float* al) {
    int bh = bx / nsplit, sp = bx - bh * nsplit;
    int b = bh >> 3, h = bh & 7;
    int cpb = 32 / nsplit;
    const int* mt = Mtop + bh * UU;

    for (int i = tid; i < UU * DIM / 8; i += 256) {
        int u = i >> 3, dv = (i & 7) * 8;
        int row = mt[u];
        const float* qp = Qg + ((size_t)(b * L_SEQ + row) * NH + h) * DIM + dv;
        *(float4*)&qs[u * DIM + dv]     = *(const float4*)qp;
        *(float4*)&qs[u * DIM + dv + 4] = *(const float4*)(qp + 4);
    }
    if (tid < UU) { mm[tid] = -INFINITY; ll[tid] = 0.f; }

    int d0 = (tid & 31) * 2, ugp = tid >> 5;
    float o0[5], o1[5];
    #pragma unroll
    for (int j = 0; j < 5; ++j) { o0[j] = 0.f; o1[j] = 0.f; }

    for (int c = 0; c < cpb; ++c) {
        int k0 = (sp * cpb + c) * 64;
        if (c) __syncthreads();
        for (int i = tid; i < 64 * DIM / 8; i += 256) {
            int r = i >> 3, dv = (i & 7) * 8;
            const float* kp = Kg + ((size_t)(b * L_SEQ + k0 + r) * NH + h) * DIM + dv;
            *(float4*)&ks[r * 68 + dv]     = *(const float4*)kp;
            *(float4*)&ks[r * 68 + dv + 4] = *(const float4*)(kp + 4);
        }
        __syncthreads();

        {
            int k = tid & 63, ug = tid >> 6;
            float acc[10];
            #pragma unroll
            for (int j = 0; j < 10; ++j) acc[j] = 0.f;
            for (int d = 0; d < DIM; d += 4) {
                float4 kv = *(float4*)&ks[k * 68 + d];
                #pragma unroll
                for (int j = 0; j < 10; ++j) {
                    float4 qv = *(float4*)&qs[(ug * 10 + j) * DIM + d];
                    acc[j] = fmaf(qv.x, kv.x, acc[j]);
                    acc[j] = fmaf(qv.y, kv.y, acc[j]);
                    acc[j] = fmaf(qv.z, kv.z, acc[j]);
                    acc[j] = fmaf(qv.w, kv.w, acc[j]);
                }
            }
            #pragma unroll
            for (int j = 0; j < 10; ++j) ps[(ug * 10 + j) * 68 + k] = acc[j] * 0.125f;
        }
        __syncthreads();

        for (int i = tid; i < 64 * DIM / 8; i += 256) {
            int r = i >> 3, dv = (i & 7) * 8;
            const float* vp = Vg + ((size_t)(b * L_SEQ + k0 + r) * NH + h) * DIM + dv;
            *(float4*)&ks[r * 68 + dv]     = *(const float4*)vp;
            *(float4*)&ks[r * 68 + dv + 4] = *(const float4*)(vp + 4);
        }
        if (tid < UU) {
            float mc = -INFINITY;
            for (int k = 0; k < 64; ++k) mc = fmaxf(mc, ps[tid * 68 + k]);
            float mn = fmaxf(mm[tid], mc);
            float a = __expf(mm[tid] - mn);
            float s = 0.f;
            for (int k = 0; k < 64; ++k) {
                float e = __expf(ps[tid * 68 + k] - mn);
                ps[tid * 68 + k] = e;
                s += e;
            }
            ll[tid] = ll[tid] * a + s;
            mm[tid] = mn;
            al[tid] = a;
        }
        __syncthreads();

        {
            #pragma unroll
            for (int j = 0; j < 5; ++j) {
                float a = al[ugp * 5 + j];
                o0[j] *= a; o1[j] *= a;
            }
            for (int k = 0; k < 64; k += 4) {
                float vf0[4], vf1[4];
                #pragma unroll
                for (int kk = 0; kk < 4; ++kk) {
                    float2 vv = *(float2*)&ks[(k + kk) * 68 + d0];
                    vf0[kk] = vv.x;
                    vf1[kk] = vv.y;
                }
                #pragma unroll
                for (int j = 0; j < 5; ++j) {
                    float4 pv = *(float4*)&ps[(ugp * 5 + j) * 68 + k];
                    o0[j] = fmaf(pv.x, vf0[0], o0[j]); o1[j] = fmaf(pv.x, vf1[0], o1[j]);
                    o0[j] = fmaf(pv.y, vf0[1], o0[j]); o1[j] = fmaf(pv.y, vf1[1], o1[j]);
                    o0[j] = fmaf(pv.z, vf0[2], o0[j]); o1[j] = fmaf(pv.z, vf1[2], o1[j]);
                    o0[j] = fmaf(pv.w, vf0[3], o0[j]); o1[j] = fmaf(pv.w, vf1[3], o1[j]);
                }
            }
        }
    }

    if (!direct) {
        if (tid < UU) {
            pm[((size_t)bh * nsplit + sp) * UU + tid] = mm[tid];
            pl[((size_t)bh * nsplit + sp) * UU + tid] = ll[tid];
        }
        size_t basep = ((size_t)bh * nsplit + sp) * UU * DIM;
        #pragma unroll
        for (int j = 0; j < 5; ++j) {
            *(float2*)&pO[basep + (size_t)(ugp * 5 + j) * DIM + d0] = make_float2(o0[j], o1[j]);
        }
    } else {
        #pragma unroll
        for (int j = 0; j < 5; ++j) {
            int u = ugp * 5 + j;
            int row = mt[u];
            float inv = 1.0f / ll[u];
            size_t o = ((size_t)(b * L_SEQ + row) * NH + h) * DIM + d0;
            out[o]     = o0[j] * inv;
            out[o + 1] = o1[j] * inv;
        }
    }
}

// ======================= fused stage kernels =======================

// stage1: blocks [0,2048) m-score (4 l per block, 80KB LDS) ; [2048,4096) csum8
__global__ __launch_bounds__(256) void stage1_kernel(const float* __restrict__ Qg,
                                                     const float* __restrict__ Kg,
                                                     const int* __restrict__ idx,
                                                     const float* __restrict__ Vg,
                                                     float* __restrict__ M,
                                                     float* __restrict__ cs8) {
    __shared__ float ksm[4 * 5120];   // 80KB: 4 waves x 10 K rows
    int bx = blockIdx.x, tid = threadIdx.x;
    if (bx < 2048) {
        m_body(Qg, Kg, idx, M, bx, tid, ksm);
    } else {
        int wid = (bx - 2048) * 4 + (tid >> 6);
        csum8_body(Vg, cs8, wid, tid & 63);
    }
}

// stage2: blocks [0,32) topk radix ; [32,64) prefix over cs8
__global__ __launch_bounds__(256) void stage2_kernel(const float* __restrict__ M,
                                                     int* __restrict__ Mtop,
                                                     float* __restrict__ cs8) {
    __shared__ unsigned hist[256];
    __shared__ unsigned suf[256];
    __shared__ int eq_list[64];
    __shared__ unsigned sh_bin, sh_need, sh_cnt, sh_eqc;
    __shared__ float buf[256 * 64];   // prefix branch (64 KB)
    int bx = blockIdx.x, tid = threadIdx.x;

    if (bx < 32) {
        int bh = bx;
        const float* Mrow = M + (size_t)bh * L_SEQ;
        int base = tid * 8;
        float4 a0 = *(const float4*)(Mrow + base);
        float4 a1 = *(const float4*)(Mrow + base + 4);
        float fv[8] = {a0.x, a0.y, a0.z, a0.w, a1.x, a1.y, a1.z, a1.w};
        unsigned key[8];
        #pragma unroll
        for (int j = 0; j < 8; ++j) {
            unsigned u = __float_as_uint(fv[j]);
            key[j] = (u & 0x80000000u) ? ~u : (u | 0x80000000u);
        }
        unsigned actmask = 0xffu;
        unsigned thresh = 0;
        int need = UU;
        #pragma unroll
        for (int shift = 24; shift >= 0; shift -= 8) {
            hist[tid] = 0;
            __syncthreads();
            #pragma unroll
            for (int j = 0; j < 8; ++j)
                if ((actmask >> j) & 1u)
                    atomicAdd(&hist[(key[j] >> shift) & 0xffu], 1u);
            __syncthreads();
            if (tid < 64) {
                int b0 = tid * 4;
                unsigned h0 = hist[b0], h1 = hist[b0 + 1], h2 = hist[b0 + 2], h3 = hist[b0 + 3];
                unsigned loc = h0 + h1 + h2 + h3;
                unsigned s = loc;
                #pragma unroll
                for (int off = 1; off < 64; off <<= 1) {
                    unsigned o = __shfl_down(s, off, 64);
                    if (tid + off < 64) s += o;
                }
                unsigned tail = s - loc;
                suf[b0 + 3] = tail;
                suf[b0 + 2] = tail + h3;
                suf[b0 + 1] = tail + h3 + h2;
                suf[b0 + 0] = tail + h3 + h2 + h1;
            }
            __syncthreads();
            {
                int sb = (int)suf[tid];
                if (sb < need && sb + (int)hist[tid] >= need) {
                    sh_bin = (unsigned)tid;
                    sh_need = (unsigned)(need - sb);
                }
            }
            __syncthreads();
            unsigned Bb = sh_bin;
            need = (int)sh_need;
            thresh = (thresh << 8) | Bb;
            #pragma unroll
            for (int j = 0; j < 8; ++j)
                if ((actmask >> j) & 1u)
                    if (((key[j] >> shift) & 0xffu) != Bb) actmask &= ~(1u << j);
            __syncthreads();
        }
        if (tid == 0) { sh_cnt = 0; sh_eqc = 0; }
        __syncthreads();
        int* op = Mtop + bh * UU;
        #pragma unroll
        for (int j = 0; j < 8; ++j) {
            if (key[j] > thresh) {
                unsigned p = atomicAdd(&sh_cnt, 1u);
                op[p] = base + j;
            } else if (key[j] == thresh) {
                unsigned p = atomicAdd(&sh_eqc, 1u);
                if (p < 64) eq_list[p] = base + j;
            }
        }
        __syncthreads();
        unsigned cnt = sh_cnt, eqc = sh_eqc;
        if ((int)eqc == need) {
            if (tid < (unsigned)need) op[cnt + tid] = eq_list[tid];
        } else if (tid == 0) {
            if (eqc <= 64u) {
                for (int t = 0; t < need; ++t) {
                    int mi = t;
                    for (int j = t + 1; j < (int)eqc; ++j)
                        if (eq_list[j] < eq_list[mi]) mi = j;
                    int tmp = eq_list[t]; eq_list[t] = eq_list[mi]; eq_list[mi] = tmp;
                    op[cnt + t] = eq_list[t];
                }
            } else {
                int taken = 0;
                for (int i = 0; i < L_SEQ && taken < need; ++i) {
                    unsigned u = __float_as_uint(Mrow[i]);
                    unsigned k = (u & 0x80000000u) ? ~u : (u | 0x80000000u);
                    if (k == thresh) op[cnt + taken++] = i;
                }
            }
        }
    } else {
        int bh = bx - 32;
        float* g = cs8 + (size_t)bh * 16384;
        for (int it = 0; it < 16; ++it) {
            int i = it * 1024 + tid * 4;
            *(float4*)&buf[i] = *(const float4*)&g[i];
        }
        __syncthreads();
        if (tid < 64) {
            float run = 0.f;
            for (int c = 0; c < 256; ++c) {
                float t = buf[c * 64 + tid];
                buf[c * 64 + tid] = run;
                run += t;
            }
        }
        __syncthreads();
        for (int it = 0; it < 16; ++it) {
            int i = it * 1024 + tid * 4;
            *(float4*)&g[i] = *(const float4*)&buf[i];
        }
    }
}

// stage3: blocks [0,nattn) attention partials ; [nattn, nattn+2048) cumsum write
__global__ __launch_bounds__(256) void stage3_kernel(const float* __restrict__ Qg,
                                                     const float* __restrict__ Kg,
                                                     const float* __restrict__ Vg,
                                                     const int* __restrict__ Mtop,
                                                     const float* __restrict__ cs8,
                                                     float* __restrict__ pm,
                                                     float* __restrict__ pl,
                                                     float* __restrict__ pO,
                                                     float* __restrict__ out,
                                                     int nattn, int nsplit) {
    __shared__ float qs[UU * DIM];
    __shared__ float ks[64 * 68];
    __shared__ float ps[UU * 68];
    __shared__ float mm[UU], ll[UU], al[UU];
    int bx = blockIdx.x, tid = threadIdx.x;
    if (bx < nattn) {
        attn_body(Qg, Kg, Vg, Mtop, pm, pl, pO, out, nsplit, 0, bx, tid,
                  qs, ks, ps, mm, ll, al);
    } else {
        int wid = (bx - nattn) * 4 + (tid >> 6);
        write8_body(Vg, cs8, out, wid, tid & 63);
    }
}

// standalone attention (fallback tiers; direct mode)
__global__ __launch_bounds__(256) void attn_kernel(const float* __restrict__ Qg,
                                                   const float* __restrict__ Kg,
                                                   const float* __restrict__ Vg,
                                                   const int* __restrict__ Mtop,
                                                   float* __restrict__ pm,
                                                   float* __restrict__ pl,
                                                   float* __restrict__ pO,
                                                   float* __restrict__ out,
                                                   int nsplit, int direct) {
    __shared__ float qs[UU * DIM];
    __shared__ float ks[64 * 68];
    __shared__ float ps[UU * 68];
    __shared__ float mm[UU], ll[UU], al[UU];
    attn_body(Qg, Kg, Vg, Mtop, pm, pl, pO, out, nsplit, direct,
              blockIdx.x, threadIdx.x, qs, ks, ps, mm, ll, al);
}

// stage4: combine partials + scatter attn rows
__global__ __launch_bounds__(256) void combine_kernel(const float* __restrict__ pm,
                                                      const float* __restrict__ pl,
                                                      const float* __restrict__ pO,
                                                      const int* __restrict__ Mtop,
                                                      float* __restrict__ out, int nsplit) {
    int wid = blockIdx.x * 4 + (threadIdx.x >> 6);
    int lane = threadIdx.x & 63;
    int u = wid % UU;
    int bh = wid / UU;
    int b = bh >> 3, h = bh & 7;
    float mg = -INFINITY;
    for (int c = 0; c < nsplit; ++c) mg = fmaxf(mg, pm[((size_t)bh * nsplit + c) * UU + u]);
    float acc = 0.f, lsum = 0.f;
    for (int c = 0; c < nsplit; ++c) {
        size_t pb = ((size_t)bh * nsplit + c) * UU + u;
        float w = __expf(pm[pb] - mg);
        lsum = fmaf(pl[pb], w, lsum);
        acc = fmaf(w, pO[pb * DIM + lane], acc);
    }
    int row = Mtop[bh * UU + u];
    out[((size_t)(b * L_SEQ + row) * NH + h) * DIM + lane] = acc / lsum;
}

// fused cumsum fallback (ultra-slim ws)
__global__ __launch_bounds__(256) void csum_fused_kernel(const float* __restrict__ Vg,
                                                         float* __restrict__ out) {
    __shared__ float css[32 * 64];
    int bh = blockIdx.x, tid = threadIdx.x;
    int b = bh >> 3, h = bh & 7;
    int cc = tid >> 3, d8 = (tid & 7) * 8;
    size_t off = ((size_t)(b * L_SEQ + cc * 64) * NH + h) * DIM + d8;
    const float* Vp = Vg + off;
    float s[8];
    #pragma unroll
    for (int j = 0; j < 8; ++j) s[j] = 0.f;
    for (int l = 0; l < 64; ++l) {
        float4 r0 = *(const float4*)(Vp + (size_t)l * NHD);
        float4 r1 = *(const float4*)(Vp + (size_t)l * NHD + 4);
        s[0] += r0.x; s[1] += r0.y; s[2] += r0.z; s[3] += r0.w;
        s[4] += r1.x; s[5] += r1.y; s[6] += r1.z; s[7] += r1.w;
    }
    #pragma unroll
    for (int j = 0; j < 8; ++j) css[cc * 64 + d8 + j] = s[j];
    __syncthreads();
    if (tid < 64) {
        float run = 0.f;
        for (int c = 0; c < 32; ++c) {
            float t = css[c * 64 + tid];
            css[c * 64 + tid] = run;
            run += t;
        }
    }
    __syncthreads();
    float r8[8];
    #pragma unroll
    for (int j = 0; j < 8; ++j) r8[j] = css[cc * 64 + d8 + j];
    float* Op = out + off;
    for (int l = 0; l < 64; ++l) {
        float4 r0 = *(const float4*)(Vp + (size_t)l * NHD);
        float4 r1 = *(const float4*)(Vp + (size_t)l * NHD + 4);
        r8[0] += r0.x; r8[1] += r0.y; r8[2] += r0.z; r8[3] += r0.w;
        r8[4] += r1.x; r8[5] += r1.y; r8[6] += r1.z; r8[7] += r1.w;
        *(float4*)(Op + (size_t)l * NHD)     = make_float4(r8[0], r8[1], r8[2], r8[3]);
        *(float4*)(Op + (size_t)l * NHD + 4) = make_float4(r8[4], r8[5], r8[6], r8[7]);
    }
}

extern "C" void kernel_launch(void* const* d_in, const int* in_sizes, int n_in,
                              void* d_out, int out_size, void* d_ws, size_t ws_size,
                              hipStream_t stream) {
    const float* Q = (const float*)d_in[0];
    const float* K = (const float*)d_in[1];
    const float* V = (const float*)d_in[2];
    const int* idx = (const int*)d_in[3];
    float* out = (float*)d_out;
    float* wsf = (float*)d_ws;

    const int n = 8;  // key-splits for attention partials
    // ws floats: M[65536] | Mtop[1280 int] | pm[10240] | pl[10240] | pO[655360] | cs8[524288]
    size_t need_full = (size_t)(65536 + 1280 + 1280 * n * 2 + 81920 * n + 524288) * 4;

    if (ws_size >= need_full) {
        float* M    = wsf;
        int*   Mtop = (int*)(wsf + 65536);
        float* pm   = wsf + 66816;
        float* pl   = pm + 1280 * (size_t)n;
        float* pO   = pl + 1280 * (size_t)n;
        float* cs8  = pO + 81920 * (size_t)n;
        stage1_kernel<<<4096, 256, 0, stream>>>(Q, K, idx, V, M, cs8);
        stage2_kernel<<<64, 256, 0, stream>>>(M, Mtop, cs8);
        stage3_kernel<<<32 * n + 2048, 256, 0, stream>>>(Q, K, V, Mtop, cs8,
                                                         pm, pl, pO, out, 32 * n, n);
        combine_kernel<<<320, 256, 0, stream>>>(pm, pl, pO, Mtop, out, n);
    } else if (ws_size >= (size_t)(66816 + 524288) * 4) {
        float* M    = wsf;
        int*   Mtop = (int*)(wsf + 65536);
        float* cs8  = wsf + 66816;
        stage1_kernel<<<4096, 256, 0, stream>>>(Q, K, idx, V, M, cs8);
        stage2_kernel<<<64, 256, 0, stream>>>(M, Mtop, cs8);
        stage3_kernel<<<2048, 256, 0, stream>>>(Q, K, V, Mtop, cs8,
                                                nullptr, nullptr, nullptr, out, 0, 1);
        attn_kernel<<<32, 256, 0, stream>>>(Q, K, V, Mtop, nullptr, nullptr, nullptr,
                                            out, 1, 1);
    } else {
        float* M    = (float*)d_out;
        int*   Mtop = (int*)d_ws;
        stage1_kernel<<<2048, 256, 0, stream>>>(Q, K, idx, nullptr, M, nullptr);
        stage2_kernel<<<32, 256, 0, stream>>>(M, Mtop, nullptr);
        csum_fused_kernel<<<32, 256, 0, stream>>>(V, out);
        attn_kernel<<<32, 256, 0, stream>>>(Q, K, V, Mtop, nullptr, nullptr, nullptr,
                                            out, 1, 1);
    }
}